// Round 8
// baseline (165.065 us; speedup 1.0000x reference)
//
#include <hip/hip_runtime.h>
#include <math.h>

#define BATCH 4
#define CH    256
#define NPIX  4096
#define DQK   32

typedef short          s16;
typedef unsigned int   uint_t;
typedef __attribute__((ext_vector_type(8)))  short short8;    // 8 bf16
typedef __attribute__((ext_vector_type(4)))  float floatx4;   // 16x16 C/D
typedef __attribute__((ext_vector_type(16))) float floatx16;  // 32x32 C/D

__device__ __forceinline__ s16 f2bf(float f) {
  union { float f; uint_t u; } v; v.f = f;
  return (s16)((v.u + 0x8000u) >> 16);
}
__device__ __forceinline__ float bf2f(s16 u) {
  union { uint_t u; float f; } v; v.u = ((uint_t)(unsigned short)u) << 16; return v.f;
}
__device__ __forceinline__ uint_t pk2(float a, float b) {
  union { float f; uint_t u; } x, y; x.f = a; y.f = b;
  return (((y.u + 0x8000u) >> 16) << 16) | ((x.u + 0x8000u) >> 16);
}

// ============ prepack: W (fp32, rows Q32|K32|V256) -> bf16 [320][256] ======
__global__ __launch_bounds__(256) void prepack(
    const float* __restrict__ Wq, const float* __restrict__ bq,
    const float* __restrict__ Wk, const float* __restrict__ bk,
    const float* __restrict__ Wv, const float* __restrict__ bv,
    s16* __restrict__ Wbf, float* __restrict__ Bsw)
{
  const int gid = blockIdx.x * 256 + threadIdx.x;   // grid 80
  const int e0  = gid * 4;
  const int row = e0 >> 8, col = e0 & 255;
  const float* src = (row < 32) ? Wq + (size_t)row * 256
                   : (row < 64) ? Wk + (size_t)(row - 32) * 256
                                : Wv + (size_t)(row - 64) * 256;
  float4 f = *(const float4*)(src + col);
  uint2 o; o.x = pk2(f.x, f.y); o.y = pk2(f.z, f.w);
  *(uint2*)(Wbf + e0) = o;
  if (gid < 320)
    Bsw[gid] = (gid < 32) ? bq[gid] : (gid < 64) ? bk[gid - 32] : bv[gid - 64];
}

// ============ proj: UNCHANGED (held for attribution) =======================
__global__ __launch_bounds__(256, 2) void proj_mfma(
    const float* __restrict__ x, const s16* __restrict__ Wbf,
    const float* __restrict__ Bsw,
    s16* __restrict__ Qw, s16* __restrict__ Kw, s16* __restrict__ Vw)
{
  const int b  = blockIdx.x >> 7;
  const int n0 = (blockIdx.x & 127) << 5;
  const int t  = threadIdx.x;

  __shared__ s16 Xs[32][264];
  __shared__ s16 Os[256][40];

  const float* xb = x + (size_t)b * CH * NPIX + n0;
  #pragma unroll
  for (int i = 0; i < 2; ++i) {
    int task = i * 256 + t;
    int ncg  = task & 7;
    int kcg  = task >> 3;
    const float* src = xb + (size_t)(kcg * 4) * NPIX + ncg * 4;
    float rows[4][4];
    *(float4*)&rows[0][0] = *(const float4*)(src);
    *(float4*)&rows[1][0] = *(const float4*)(src + NPIX);
    *(float4*)&rows[2][0] = *(const float4*)(src + 2 * NPIX);
    *(float4*)&rows[3][0] = *(const float4*)(src + 3 * NPIX);
    #pragma unroll
    for (int c = 0; c < 4; ++c) {
      uint2 pk;
      pk.x = pk2(rows[0][c], rows[1][c]);
      pk.y = pk2(rows[2][c], rows[3][c]);
      *(uint2*)&Xs[ncg * 4 + c][kcg * 4] = pk;
    }
  }
  __syncthreads();

  const int w    = t >> 6;
  const int l15  = t & 15;
  const int quad = (t & 63) >> 4;

  floatx4 acc[5][2];
  #pragma unroll
  for (int si = 0; si < 5; ++si)
    #pragma unroll
    for (int nt = 0; nt < 2; ++nt) acc[si][nt] = (floatx4){0.f, 0.f, 0.f, 0.f};

  short8 afc[5], afn[5];
  #pragma unroll
  for (int si = 0; si < 5; ++si) {
    const int s = w + si * 4;
    afc[si] = *(const short8*)(Wbf + (size_t)(s * 16 + l15) * 256 + quad * 8);
  }
  for (int kc = 0; kc < 8; ++kc) {
    const int k0  = kc * 32;
    const int kn0 = (kc < 7) ? k0 + 32 : 0;
    #pragma unroll
    for (int si = 0; si < 5; ++si) {
      const int s = w + si * 4;
      afn[si] = *(const short8*)(Wbf + (size_t)(s * 16 + l15) * 256 + kn0 + quad * 8);
    }
    short8 bf[2];
    #pragma unroll
    for (int nt = 0; nt < 2; ++nt)
      bf[nt] = *(const short8*)&Xs[l15 + 16 * nt][k0 + quad * 8];
    #pragma unroll
    for (int si = 0; si < 5; ++si)
      #pragma unroll
      for (int nt = 0; nt < 2; ++nt)
        acc[si][nt] = __builtin_amdgcn_mfma_f32_16x16x32_bf16(afc[si], bf[nt], acc[si][nt], 0, 0, 0);
    #pragma unroll
    for (int si = 0; si < 5; ++si) afc[si] = afn[si];
  }

  #pragma unroll
  for (int si = 0; si < 5; ++si) {
    const int s = w + si * 4;
    float4 bb = *(const float4*)(Bsw + 16 * s + quad * 4);
    #pragma unroll
    for (int nt = 0; nt < 2; ++nt) {
      const int px  = 16 * nt + l15;
      float v0 = acc[si][nt][0] + bb.x;
      float v1 = acc[si][nt][1] + bb.y;
      float v2 = acc[si][nt][2] + bb.z;
      float v3 = acc[si][nt][3] + bb.w;
      if (s < 4) {
        s16* dst = (s < 2) ? Qw : Kw;
        int d0 = (s & 1) * 16 + quad * 4;
        uint2 pq; pq.x = pk2(v0, v1); pq.y = pk2(v2, v3);
        *(uint2*)(dst + ((size_t)b * NPIX + n0 + px) * DQK + d0) = pq;
      } else {
        const int c0 = (s - 4) * 16 + quad * 4;
        Os[c0 + 0][px] = f2bf(v0);
        Os[c0 + 1][px] = f2bf(v1);
        Os[c0 + 2][px] = f2bf(v2);
        Os[c0 + 3][px] = f2bf(v3);
      }
    }
  }
  __syncthreads();
  #pragma unroll
  for (int rep = 0; rep < 4; ++rep) {
    const int task = rep * 256 + t;
    const int ch   = task >> 2;
    const int seg  = task & 3;
    *(uint4*)(Vw + ((size_t)b * CH + ch) * NPIX + n0 + seg * 8) =
        *(const uint4*)&Os[ch][seg * 8];
  }
}

// ============ attn: key-split flash, 32x32 PV, bf16 partials ===============
// grid 512 = (b, qt, ks). Block: 64 q, keys [ks*2048, +2048), ALL 256 ch.
// 8 waves; wave w: S^T key-strip 16w of each 128-key tile + PV ch 32w..32w+31.
// No softmax max (p = exp(s), partials exactly additive across ks).
__global__ __launch_bounds__(512, 4) void attn_mfma(
    const s16* __restrict__ Qw, const s16* __restrict__ Kw,
    const s16* __restrict__ Vw, s16* __restrict__ Op, float* __restrict__ Lp)
{
  const int bi = blockIdx.x;
  const int b  = (bi & 7) >> 1;                  // batch per 2 XCDs
  const int ks = (bi >> 3) & 1;                  // key half
  const int qt = ((bi >> 4) << 1) | (bi & 1);    // 0..63
  const int n0 = qt * 64;
  const int km0 = ks * 2048;
  const int t  = threadIdx.x;
  const int w    = t >> 6;
  const int l15  = t & 15;
  const int quad = (t & 63) >> 4;
  const int l31  = t & 31;
  const int half = (t & 63) >> 5;

  __shared__ s16  Pt[2][64][136];                // P^T ring [q][key]
  __shared__ float Lsum[64][8];

  // Q B-frags (16x16x32): B[d=quad*8+j][q=16tq+l15]
  const s16* qbase = Qw + ((size_t)b * NPIX + n0) * DQK;
  short8 qb[4];
  #pragma unroll
  for (int tq = 0; tq < 4; ++tq)
    qb[tq] = *(const short8*)(qbase + (size_t)(16 * tq + l15) * DQK + quad * 8);

  floatx16 o0, o1;
  #pragma unroll
  for (int i = 0; i < 16; ++i) { o0[i] = 0.f; o1[i] = 0.f; }
  float l_part[4] = {0.f, 0.f, 0.f, 0.f};

  const s16* kbase = Kw + ((size_t)b * NPIX + km0) * DQK;
  const s16* vrow  = Vw + ((size_t)b * CH + 32 * w + l31) * NPIX + km0;  // V A-frag row

  // prefetch tile 0
  short8 ka_c = *(const short8*)(kbase + (size_t)(16 * w + l15) * DQK + quad * 8);
  short8 va[8];
  #pragma unroll
  for (int s = 0; s < 8; ++s)
    va[s] = *(const short8*)(vrow + s * 16 + half * 8);

  int buf = 0;
  for (int kt = 0; kt < 16; ++kt) {
    const int m0  = kt * 128;
    const int mn0 = (kt < 15) ? m0 + 128 : 0;

    // ---- S^T strip (16x16x32): rows=keys 16w+quad*4+r, cols=q=16tq+l15 ----
    floatx4 sacc[4];
    #pragma unroll
    for (int tq = 0; tq < 4; ++tq)
      sacc[tq] = __builtin_amdgcn_mfma_f32_16x16x32_bf16(
                   ka_c, qb[tq], (floatx4){0.f, 0.f, 0.f, 0.f}, 0, 0, 0);

    short8 ka_n = *(const short8*)(kbase + (size_t)(mn0 + 16 * w + l15) * DQK + quad * 8);

    // ---- p = exp(s), pack to Pt, strip l sums ----
    #pragma unroll
    for (int tq = 0; tq < 4; ++tq) {
      float p0 = __expf(sacc[tq][0]);
      float p1 = __expf(sacc[tq][1]);
      float p2 = __expf(sacc[tq][2]);
      float p3 = __expf(sacc[tq][3]);
      float ts = (p0 + p1) + (p2 + p3);
      uint2 pk; pk.x = pk2(p0, p1); pk.y = pk2(p2, p3);
      *(uint2*)&Pt[buf][16 * tq + l15][16 * w + quad * 4] = pk;
      ts += __shfl_xor(ts, 16);
      ts += __shfl_xor(ts, 32);
      l_part[tq] += ts;
    }
    __syncthreads();   // Pt[buf] ready (2-deep ring -> 1 barrier/tile)

    // ---- PV (32x32x16): O[32ch][64q] += V[32ch][128k]·P^T[128k][64q] ----
    #pragma unroll
    for (int s = 0; s < 8; ++s) {
      short8 pb0 = *(const short8*)&Pt[buf][l31][16 * s + half * 8];
      short8 pb1 = *(const short8*)&Pt[buf][32 + l31][16 * s + half * 8];
      o0 = __builtin_amdgcn_mfma_f32_32x32x16_bf16(va[s], pb0, o0, 0, 0, 0);
      o1 = __builtin_amdgcn_mfma_f32_32x32x16_bf16(va[s], pb1, o1, 0, 0, 0);
      // slot free -> reload for next tile
      va[s] = *(const short8*)(vrow + mn0 + 16 * s + half * 8);
    }
    ka_c = ka_n;
    buf ^= 1;
  }

  // ---- l: per-wave partials -> block sum -> ws ----
  if (quad == 0) {
    #pragma unroll
    for (int tq = 0; tq < 4; ++tq) Lsum[16 * tq + l15][w] = l_part[tq];
  }
  __syncthreads();
  if (t < 64) {
    float4 s0 = *(const float4*)&Lsum[t][0];
    float4 s1 = *(const float4*)&Lsum[t][4];
    Lp[(((size_t)b * 2 + ks) * 64 + qt) * 64 + t] =
        ((s0.x + s0.y) + (s0.z + s0.w)) + ((s1.x + s1.y) + (s1.z + s1.w));
  }

  // ---- O partial -> ws bf16 : Op[b][ks][qt][ch][q] ----
  s16* ob = Op + (((size_t)b * 2 + ks) * 64 + qt) * (256 * 64);
  #pragma unroll
  for (int reg = 0; reg < 16; ++reg) {
    const int ch = 32 * w + (reg & 3) + 8 * (reg >> 2) + 4 * half;
    ob[ch * 64 + l31]      = f2bf(o0[reg]);
    ob[ch * 64 + 32 + l31] = f2bf(o1[reg]);
  }
}

// ============ merge: out = x + (O0+O1)/(l0+l1) =============================
__global__ __launch_bounds__(256) void reduce_merge(
    const s16* __restrict__ Op, const float* __restrict__ Lp,
    const float* __restrict__ x, float* __restrict__ out)
{
  const size_t e0 = ((size_t)blockIdx.x * 256 + threadIdx.x) * 8;  // grid 2048
  const int n  = (int)(e0 & 4095);
  const int ch = (int)((e0 >> 12) & 255);
  const int b  = (int)(e0 >> 20);
  const int qt = n >> 6, q = n & 63;

  const size_t p0 = (((size_t)b * 2 + 0) * 64 + qt) * (256 * 64) + ch * 64 + q;
  const size_t p1 = (((size_t)b * 2 + 1) * 64 + qt) * (256 * 64) + ch * 64 + q;
  union { uint4 v; s16 u[8]; } O0, O1;
  O0.v = *(const uint4*)(Op + p0);
  O1.v = *(const uint4*)(Op + p1);

  const float* l0p = Lp + (((size_t)b * 2 + 0) * 64 + qt) * 64 + q;
  const float* l1p = Lp + (((size_t)b * 2 + 1) * 64 + qt) * 64 + q;
  float4 l0a = *(const float4*)l0p, l0b = *(const float4*)(l0p + 4);
  float4 l1a = *(const float4*)l1p, l1b = *(const float4*)(l1p + 4);
  float linv[8] = {
    1.f / (l0a.x + l1a.x), 1.f / (l0a.y + l1a.y),
    1.f / (l0a.z + l1a.z), 1.f / (l0a.w + l1a.w),
    1.f / (l0b.x + l1b.x), 1.f / (l0b.y + l1b.y),
    1.f / (l0b.z + l1b.z), 1.f / (l0b.w + l1b.w) };

  float4 xa = *(const float4*)(x + e0), xb = *(const float4*)(x + e0 + 4);
  float r[8] = { xa.x, xa.y, xa.z, xa.w, xb.x, xb.y, xb.z, xb.w };
  #pragma unroll
  for (int j = 0; j < 8; ++j)
    r[j] = fmaf(bf2f(O0.u[j]) + bf2f(O1.u[j]), linv[j], r[j]);
  *(float4*)(out + e0)     = make_float4(r[0], r[1], r[2], r[3]);
  *(float4*)(out + e0 + 4) = make_float4(r[4], r[5], r[6], r[7]);
}

extern "C" void kernel_launch(void* const* d_in, const int* in_sizes, int n_in,
                              void* d_out, int out_size, void* d_ws, size_t ws_size,
                              hipStream_t stream) {
  (void)in_sizes; (void)n_in; (void)out_size; (void)ws_size;
  const float* x  = (const float*)d_in[0];
  const float* Wq = (const float*)d_in[1];
  const float* bq = (const float*)d_in[2];
  const float* Wk = (const float*)d_in[3];
  const float* bk = (const float*)d_in[4];
  const float* Wv = (const float*)d_in[5];
  const float* bv = (const float*)d_in[6];
  float* out = (float*)d_out;

  // ws (bytes): Qw @0 (1M) | Kw @1M (1M) | Vw @2M (8M) | Wbf @10M (160K) |
  // Bsw @10.25M (1.25K) | Lp @10.5M (128K) | Op @11M (16M)  => 27 MiB
  unsigned char* ws = (unsigned char*)d_ws;
  s16*   Qw  = (s16*)ws;
  s16*   Kw  = (s16*)(ws + (size_t)1 * 1024 * 1024);
  s16*   Vw  = (s16*)(ws + (size_t)2 * 1024 * 1024);
  s16*   Wbf = (s16*)(ws + (size_t)10 * 1024 * 1024);
  float* Bsw = (float*)(ws + (size_t)10 * 1024 * 1024 + 256 * 1024);
  float* Lp  = (float*)(ws + (size_t)10 * 1024 * 1024 + 512 * 1024);
  s16*   Op  = (s16*)(ws + (size_t)11 * 1024 * 1024);

  hipLaunchKernelGGL(prepack, dim3(80), dim3(256), 0, stream,
                     Wq, bq, Wk, bk, Wv, bv, Wbf, Bsw);
  hipLaunchKernelGGL(proj_mfma, dim3(512), dim3(256), 0, stream,
                     x, Wbf, Bsw, Qw, Kw, Vw);
  hipLaunchKernelGGL(attn_mfma, dim3(512), dim3(512), 0, stream,
                     Qw, Kw, Vw, Op, Lp);
  hipLaunchKernelGGL(reduce_merge, dim3(2048), dim3(256), 0, stream,
                     Op, Lp, x, out);
}